// Round 5
// baseline (3940.224 us; speedup 1.0000x reference)
//
#include <hip/hip_runtime.h>

#define B_ 256
#define T_ 80
#define IN_ 39
#define H_ 256
#define G_ 1024
#define L_ 5
#define TC_ 16
#define NCH_ 5

#define XP_FLOATS   (B_ * TC_ * G_)     // 4,194,304
#define HBUF_FLOATS (B_ * T_ * H_)      // 5,242,880
#define CBUF_FLOATS (B_ * H_)           // 65,536
#define WG_FLOATS   (L_ * G_ * H_)      // 1,310,720
#define HX_U64      (2 * 32 * 2048)     // 131,072 u64 = 1 MB
#define HX_OFF_FLOATS (XP_FLOATS + HBUF_FLOATS + CBUF_FLOATS + WG_FLOATS)

#define AG __HIP_MEMORY_SCOPE_AGENT

__device__ __forceinline__ float sigm(float x) { return 1.0f / (1.0f + expf(-x)); }
__device__ __forceinline__ void fma4(float4& a, float s, const float4& w) {
    a.x = fmaf(s, w.x, a.x); a.y = fmaf(s, w.y, a.y);
    a.z = fmaf(s, w.z, a.z); a.w = fmaf(s, w.w, a.w);
}
__device__ __forceinline__ void red4(float4& a) {
    a.x += __shfl_xor(a.x, 32); a.y += __shfl_xor(a.y, 32);
    a.z += __shfl_xor(a.z, 32); a.w += __shfl_xor(a.w, 32);
}

// ---- Wg: per-slice interleaved W_hh: Wg[l][s][k][j][g] = Whh[l][g*256+s*32+j][k] ----
extern "C" __global__ void __launch_bounds__(256)
wt_kernel(const float* __restrict__ Whh, float* __restrict__ Wg) {
    const int gid = blockIdx.x * 256 + threadIdx.x;
    const int g4 = gid & 3;
    const int j  = (gid >> 2) & 31;
    const int k  = (gid >> 7) & 255;
    const int s  = (gid >> 15) & 7;
    const int l  = gid >> 18;
    Wg[gid] = Whh[((size_t)(l * 1024 + g4 * 256 + s * 32 + j)) * 256 + k];
}

// ---- projection GEMM (unchanged) ----
extern "C" __global__ void __launch_bounds__(256)
proj_kernel(const float* __restrict__ src, const float* __restrict__ Wih,
            const float* __restrict__ bihl, const float* __restrict__ bhhl,
            float* __restrict__ xp, int K, int t0) {
    __shared__ float As[16 * 68];
    __shared__ float Bs[16 * 68];
    const int tid = threadIdx.x;
    const int mt = blockIdx.x >> 4, nt = blockIdx.x & 15;
    const int tx = tid & 15, ty = tid >> 4;
    const int lr = tid >> 2, lc4 = (tid & 3) << 2;

    const int ar = mt * 64 + lr;
    const int ab = ar >> 4;
    const int at = t0 + (ar & 15);
    const float* arow = src + ((size_t)ab * T_ + at) * K;
    const float* brow = Wih + (size_t)(nt * 64 + lr) * K;

    float acc[4][4];
    #pragma unroll
    for (int i = 0; i < 4; ++i)
        #pragma unroll
        for (int j = 0; j < 4; ++j) acc[i][j] = 0.0f;

    for (int k0 = 0; k0 < K; k0 += 16) {
        __syncthreads();
        if (K == IN_) {
            #pragma unroll
            for (int i = 0; i < 4; ++i) {
                int k = k0 + lc4 + i;
                As[(lc4 + i) * 68 + lr] = (k < IN_) ? arow[k] : 0.0f;
                Bs[(lc4 + i) * 68 + lr] = (k < IN_) ? brow[k] : 0.0f;
            }
        } else {
            float4 av = *(const float4*)(arow + k0 + lc4);
            float4 bv = *(const float4*)(brow + k0 + lc4);
            As[(lc4 + 0) * 68 + lr] = av.x;
            As[(lc4 + 1) * 68 + lr] = av.y;
            As[(lc4 + 2) * 68 + lr] = av.z;
            As[(lc4 + 3) * 68 + lr] = av.w;
            Bs[(lc4 + 0) * 68 + lr] = bv.x;
            Bs[(lc4 + 1) * 68 + lr] = bv.y;
            Bs[(lc4 + 2) * 68 + lr] = bv.z;
            Bs[(lc4 + 3) * 68 + lr] = bv.w;
        }
        __syncthreads();
        #pragma unroll
        for (int kk = 0; kk < 16; ++kk) {
            float4 a4 = *(const float4*)&As[kk * 68 + ty * 4];
            float4 b4 = *(const float4*)&Bs[kk * 68 + tx * 4];
            acc[0][0] += a4.x * b4.x; acc[0][1] += a4.x * b4.y;
            acc[0][2] += a4.x * b4.z; acc[0][3] += a4.x * b4.w;
            acc[1][0] += a4.y * b4.x; acc[1][1] += a4.y * b4.y;
            acc[1][2] += a4.y * b4.z; acc[1][3] += a4.y * b4.w;
            acc[2][0] += a4.z * b4.x; acc[2][1] += a4.z * b4.y;
            acc[2][2] += a4.z * b4.z; acc[2][3] += a4.z * b4.w;
            acc[3][0] += a4.w * b4.x; acc[3][1] += a4.w * b4.y;
            acc[3][2] += a4.w * b4.z; acc[3][3] += a4.w * b4.w;
        }
    }
    const int col = nt * 64 + tx * 4;
    const float bs0 = bihl[col + 0] + bhhl[col + 0];
    const float bs1 = bihl[col + 1] + bhhl[col + 1];
    const float bs2 = bihl[col + 2] + bhhl[col + 2];
    const float bs3 = bihl[col + 3] + bhhl[col + 3];
    #pragma unroll
    for (int i = 0; i < 4; ++i) {
        const int row = mt * 64 + ty * 4 + i;
        float4 o;
        o.x = acc[i][0] + bs0; o.y = acc[i][1] + bs1;
        o.z = acc[i][2] + bs2; o.w = acc[i][3] + bs3;
        *(float4*)&xp[(size_t)row * G_ + col] = o;
    }
}

// ---- recurrence: W-stationary in LDS; h exchanged as tagged u64 atomics ----
// Publish: (tag<<32 | f32bits) relaxed agent-scope. Consumers spin on their 8
// contiguous u64 until all tags match the step id -> readiness rides with the
// data; no counter, no vmcnt drain, no extra barrier. Pipeline depth is
// self-limiting (producer step tt+2 is gated on all peers consuming tt).
extern "C" __global__ void __launch_bounds__(256, 1)
rec2_kernel(const float* __restrict__ xp, const float* __restrict__ Wg_l,
            float* __restrict__ hbuf, float* __restrict__ cbuf,
            unsigned long long* __restrict__ hx,
            int t0, int tagb, int first) {
    extern __shared__ float smem[];
    float* sW = smem;            // 32768 floats: [k][j][g]
    float* sH = smem + 32768;    // 2048 floats: hT[k][bb]
    float* sP = smem + 34816;    // 4608 floats: part[w][jj][36]

    const int tid = threadIdx.x;
    const int bid = blockIdx.x;
    const int grp = bid & 31;
    const int s   = bid >> 5;
    const int jj  = tid & 31;   // main identity: unit
    const int ks  = tid >> 5;   // main identity: k-slice
    const int w   = tid >> 6;   // wave id
    const int fb  = tid >> 5;   // finish identity: batch
    const int fj  = tid & 31;   // finish identity: unit
    const int bglob = grp * 8 + fb;
    const int unit  = s * 32 + fj;

    // load W slice into LDS (coalesced, linear)
    {
        const float4* Wgs = (const float4*)Wg_l + (size_t)s * 8192;
        float4* sW4 = (float4*)sW;
        #pragma unroll 4
        for (int i = tid; i < 8192; i += 256) sW4[i] = Wgs[i];
    }

    float creg = first ? 0.0f : cbuf[(size_t)bglob * H_ + unit];
    const float4* sW4 = (const float4*)sW;

    for (int tt = 0; tt < TC_; ++tt) {
        const int t = t0 + tt;

        // ---- phase A: gather h(t-1) into sH (hT[k][bb]) ----
        if (tt == 0) {
            if (first) {
                for (int i = tid; i < 2048; i += 256) sH[i] = 0.0f;
            } else {
                const int u = tid;
                #pragma unroll
                for (int bb = 0; bb < 8; ++bb)
                    sH[u * 8 + bb] = hbuf[((size_t)(grp * 8 + bb) * T_ + (t0 - 1)) * H_ + u];
            }
        } else {
            const unsigned exp_tag = (unsigned)(tagb + tt - 1);
            const unsigned long long* hs =
                hx + (size_t)(((tt - 1) & 1) * 32 + grp) * 2048 + (size_t)tid * 8;
            unsigned long long v[8];
            for (;;) {
                bool ok = true;
                #pragma unroll
                for (int b = 0; b < 8; ++b)
                    v[b] = __hip_atomic_load(hs + b, __ATOMIC_RELAXED, AG);
                #pragma unroll
                for (int b = 0; b < 8; ++b)
                    ok = ok && ((unsigned)(v[b] >> 32) == exp_tag);
                if (ok) break;
                __builtin_amdgcn_s_sleep(1);
            }
            #pragma unroll
            for (int b = 0; b < 8; ++b)
                sH[tid * 8 + b] = __uint_as_float((unsigned)v[b]);
        }

        // xp prefetch (finish identity; consumed in phase C)
        const size_t xrow = ((size_t)bglob * TC_ + tt) * G_ + unit;
        const float x0 = xp[xrow];
        const float x1 = xp[xrow + 256];
        const float x2 = xp[xrow + 512];
        const float x3 = xp[xrow + 768];

        __syncthreads();  // (b) sH ready (also covers initial sW load)

        // ---- phase B: main k-loop, all from LDS ----
        float4 a0 = {0,0,0,0}, a1 = {0,0,0,0}, a2 = {0,0,0,0}, a3 = {0,0,0,0};
        float4 a4 = {0,0,0,0}, a5 = {0,0,0,0}, a6 = {0,0,0,0}, a7 = {0,0,0,0};
        #pragma unroll 4
        for (int kk = 0; kk < 32; ++kk) {
            const int k = ks * 32 + kk;
            const float4 wv = sW4[k * 32 + jj];
            const float4 ha = *(const float4*)&sH[k * 8];
            const float4 hb = *(const float4*)&sH[k * 8 + 4];
            fma4(a0, ha.x, wv); fma4(a1, ha.y, wv);
            fma4(a2, ha.z, wv); fma4(a3, ha.w, wv);
            fma4(a4, hb.x, wv); fma4(a5, hb.y, wv);
            fma4(a6, hb.z, wv); fma4(a7, hb.w, wv);
        }
        // reduce ks-pairs within wave
        red4(a0); red4(a1); red4(a2); red4(a3);
        red4(a4); red4(a5); red4(a6); red4(a7);
        if ((tid & 63) < 32) {
            float4* pp = (float4*)&sP[(w * 32 + jj) * 36];
            pp[0] = a0; pp[1] = a1; pp[2] = a2; pp[3] = a3;
            pp[4] = a4; pp[5] = a5; pp[6] = a6; pp[7] = a7;
        }
        __syncthreads();  // (c) partials ready

        // ---- phase C: finish ----
        float4 g4;
        g4.x = x0; g4.y = x1; g4.z = x2; g4.w = x3;
        #pragma unroll
        for (int w2 = 0; w2 < 4; ++w2) {
            const float4 pw = *(const float4*)&sP[(w2 * 32 + fj) * 36 + fb * 4];
            g4.x += pw.x; g4.y += pw.y; g4.z += pw.z; g4.w += pw.w;
        }
        const float I = sigm(g4.x);
        const float F = sigm(g4.y);
        const float Gt = tanhf(g4.z);
        const float O = sigm(g4.w);
        creg = F * creg + I * Gt;
        const float hval = O * tanhf(creg);
        hbuf[((size_t)bglob * T_ + t) * H_ + unit] = hval;

        if (tt < TC_ - 1) {
            const unsigned long long pv =
                ((unsigned long long)(unsigned)(tagb + tt) << 32) | __float_as_uint(hval);
            __hip_atomic_store(hx + (size_t)((tt & 1) * 32 + grp) * 2048
                                  + (size_t)unit * 8 + fb,
                               pv, __ATOMIC_RELAXED, AG);
        }
    }

    cbuf[(size_t)bglob * H_ + unit] = creg;
}

// ---- final FC ----
extern "C" __global__ void __launch_bounds__(128)
fc_kernel(const float* __restrict__ hbuf, const float* __restrict__ fcw,
          const float* __restrict__ fcb, float* __restrict__ out) {
    __shared__ float wsm[256];
    const int tid = threadIdx.x;
    const int b = blockIdx.x;
    if (tid < 64) ((float4*)wsm)[tid] = ((const float4*)fcw)[tid];
    __syncthreads();
    if (tid < T_) {
        const float4* h4p = (const float4*)(hbuf + ((size_t)b * T_ + tid) * H_);
        const float4* w4p = (const float4*)wsm;
        float acc = fcb[0];
        #pragma unroll 8
        for (int k4 = 0; k4 < 64; ++k4) {
            float4 h4 = h4p[k4], w4 = w4p[k4];
            acc += h4.x * w4.x + h4.y * w4.y + h4.z * w4.z + h4.w * w4.w;
        }
        out[b * T_ + tid] = acc;
    }
}

extern "C" void kernel_launch(void* const* d_in, const int* in_sizes, int n_in,
                              void* d_out, int out_size, void* d_ws, size_t ws_size,
                              hipStream_t stream) {
    (void)in_sizes; (void)n_in; (void)out_size; (void)ws_size;
    const float* x    = (const float*)d_in[0];
    const float* Wih0 = (const float*)d_in[1];
    const float* Wihr = (const float*)d_in[2];
    const float* Whh  = (const float*)d_in[3];
    const float* bih  = (const float*)d_in[4];
    const float* bhh  = (const float*)d_in[5];
    const float* fcw  = (const float*)d_in[6];
    const float* fcb  = (const float*)d_in[7];
    float* out = (float*)d_out;
    float* ws  = (float*)d_ws;

    float* xp   = ws;
    float* hbuf = ws + XP_FLOATS;
    float* cbuf = hbuf + HBUF_FLOATS;
    float* wg   = cbuf + CBUF_FLOATS;
    unsigned long long* hx = (unsigned long long*)(ws + HX_OFF_FLOATS);

    // zero tags so no stale/garbage tag can alias a live one this launch
    hipMemsetAsync(hx, 0, HX_U64 * sizeof(unsigned long long), stream);
    hipLaunchKernelGGL(wt_kernel, dim3(WG_FLOATS / 256), dim3(256), 0, stream, Whh, wg);

    for (int l = 0; l < L_; ++l) {
        const int K = (l == 0) ? IN_ : H_;
        const float* src = (l == 0) ? x : hbuf;
        const float* Wih = (l == 0) ? Wih0 : (Wihr + (size_t)(l - 1) * G_ * H_);
        const float* Wg_l = wg + (size_t)l * (G_ * H_);
        for (int ch = 0; ch < NCH_; ++ch) {
            const int t0 = ch * TC_;
            const int tagb = (l * NCH_ + ch) * TC_ + 1;
            hipLaunchKernelGGL(proj_kernel, dim3(1024), dim3(256), 0, stream,
                               src, Wih, bih + l * G_, bhh + l * G_, xp, K, t0);
            hipLaunchKernelGGL(rec2_kernel, dim3(256), dim3(256), 157696, stream,
                               xp, Wg_l, hbuf, cbuf, hx, t0, tagb, ch == 0 ? 1 : 0);
        }
    }
    hipLaunchKernelGGL(fc_kernel, dim3(B_), dim3(128), 0, stream, hbuf, fcw, fcb, out);
}

// Round 6
// 3105.513 us; speedup vs baseline: 1.2688x; 1.2688x over previous
//
#include <hip/hip_runtime.h>

#define B_ 256
#define T_ 80
#define IN_ 39
#define H_ 256
#define G_ 1024
#define L_ 5
#define TC_ 16
#define NCH_ 5

#define XP_FLOATS   (B_ * TC_ * G_)     // 4,194,304
#define HBUF_FLOATS (B_ * T_ * H_)      // 5,242,880
#define CBUF_FLOATS (B_ * H_)           // 65,536
#define WG_FLOATS   (L_ * G_ * H_)      // 1,310,720
#define HX_U64      (2 * 32 * 2048)     // 131,072 u64 = 1 MB
#define HX_OFF_FLOATS (XP_FLOATS + HBUF_FLOATS + CBUF_FLOATS + WG_FLOATS)

#define AG __HIP_MEMORY_SCOPE_AGENT

__device__ __forceinline__ float sigm(float x) { return 1.0f / (1.0f + expf(-x)); }
__device__ __forceinline__ void fma4(float4& a, float s, const float4& w) {
    a.x = fmaf(s, w.x, a.x); a.y = fmaf(s, w.y, a.y);
    a.z = fmaf(s, w.z, a.z); a.w = fmaf(s, w.w, a.w);
}
__device__ __forceinline__ void red4(float4& a) {
    a.x += __shfl_xor(a.x, 32); a.y += __shfl_xor(a.y, 32);
    a.z += __shfl_xor(a.z, 32); a.w += __shfl_xor(a.w, 32);
}

// ---- Wg: per-slice interleaved W_hh: Wg[l][s][k][j][g] = Whh[l][g*256+s*32+j][k] ----
extern "C" __global__ void __launch_bounds__(256)
wt_kernel(const float* __restrict__ Whh, float* __restrict__ Wg) {
    const int gid = blockIdx.x * 256 + threadIdx.x;
    const int g4 = gid & 3;
    const int j  = (gid >> 2) & 31;
    const int k  = (gid >> 7) & 255;
    const int s  = (gid >> 15) & 7;
    const int l  = gid >> 18;
    Wg[gid] = Whh[((size_t)(l * 1024 + g4 * 256 + s * 32 + j)) * 256 + k];
}

// ---- projection GEMM (unchanged) ----
extern "C" __global__ void __launch_bounds__(256)
proj_kernel(const float* __restrict__ src, const float* __restrict__ Wih,
            const float* __restrict__ bihl, const float* __restrict__ bhhl,
            float* __restrict__ xp, int K, int t0) {
    __shared__ float As[16 * 68];
    __shared__ float Bs[16 * 68];
    const int tid = threadIdx.x;
    const int mt = blockIdx.x >> 4, nt = blockIdx.x & 15;
    const int tx = tid & 15, ty = tid >> 4;
    const int lr = tid >> 2, lc4 = (tid & 3) << 2;

    const int ar = mt * 64 + lr;
    const int ab = ar >> 4;
    const int at = t0 + (ar & 15);
    const float* arow = src + ((size_t)ab * T_ + at) * K;
    const float* brow = Wih + (size_t)(nt * 64 + lr) * K;

    float acc[4][4];
    #pragma unroll
    for (int i = 0; i < 4; ++i)
        #pragma unroll
        for (int j = 0; j < 4; ++j) acc[i][j] = 0.0f;

    for (int k0 = 0; k0 < K; k0 += 16) {
        __syncthreads();
        if (K == IN_) {
            #pragma unroll
            for (int i = 0; i < 4; ++i) {
                int k = k0 + lc4 + i;
                As[(lc4 + i) * 68 + lr] = (k < IN_) ? arow[k] : 0.0f;
                Bs[(lc4 + i) * 68 + lr] = (k < IN_) ? brow[k] : 0.0f;
            }
        } else {
            float4 av = *(const float4*)(arow + k0 + lc4);
            float4 bv = *(const float4*)(brow + k0 + lc4);
            As[(lc4 + 0) * 68 + lr] = av.x;
            As[(lc4 + 1) * 68 + lr] = av.y;
            As[(lc4 + 2) * 68 + lr] = av.z;
            As[(lc4 + 3) * 68 + lr] = av.w;
            Bs[(lc4 + 0) * 68 + lr] = bv.x;
            Bs[(lc4 + 1) * 68 + lr] = bv.y;
            Bs[(lc4 + 2) * 68 + lr] = bv.z;
            Bs[(lc4 + 3) * 68 + lr] = bv.w;
        }
        __syncthreads();
        #pragma unroll
        for (int kk = 0; kk < 16; ++kk) {
            float4 a4 = *(const float4*)&As[kk * 68 + ty * 4];
            float4 b4 = *(const float4*)&Bs[kk * 68 + tx * 4];
            acc[0][0] += a4.x * b4.x; acc[0][1] += a4.x * b4.y;
            acc[0][2] += a4.x * b4.z; acc[0][3] += a4.x * b4.w;
            acc[1][0] += a4.y * b4.x; acc[1][1] += a4.y * b4.y;
            acc[1][2] += a4.y * b4.z; acc[1][3] += a4.y * b4.w;
            acc[2][0] += a4.z * b4.x; acc[2][1] += a4.z * b4.y;
            acc[2][2] += a4.z * b4.z; acc[2][3] += a4.z * b4.w;
            acc[3][0] += a4.w * b4.x; acc[3][1] += a4.w * b4.y;
            acc[3][2] += a4.w * b4.z; acc[3][3] += a4.w * b4.w;
        }
    }
    const int col = nt * 64 + tx * 4;
    const float bs0 = bihl[col + 0] + bhhl[col + 0];
    const float bs1 = bihl[col + 1] + bhhl[col + 1];
    const float bs2 = bihl[col + 2] + bhhl[col + 2];
    const float bs3 = bihl[col + 3] + bhhl[col + 3];
    #pragma unroll
    for (int i = 0; i < 4; ++i) {
        const int row = mt * 64 + ty * 4 + i;
        float4 o;
        o.x = acc[i][0] + bs0; o.y = acc[i][1] + bs1;
        o.z = acc[i][2] + bs2; o.w = acc[i][3] + bs3;
        *(float4*)&xp[(size_t)row * G_ + col] = o;
    }
}

// ---- recurrence: W-stationary in LDS; tagged u64 h-exchange, scout-gated ----
// Producer: per-thread fire-and-forget relaxed agent-scope tagged store
// (tag<<32 | f32bits). No drain, no barrier, no flag.
// Consumer: 8 scout threads poll the 8 per-slice sentinel words only; after
// they fire, all threads one-shot load their 8 u64 and verify each tag
// (re-loading rare stragglers). Polling traffic = 64B/block/round instead of
// round-5's 16KB. Correct under any XCD mapping: every word is tag-verified.
extern "C" __global__ void __launch_bounds__(256, 1)
rec2_kernel(const float* __restrict__ xp, const float* __restrict__ Wg_l,
            float* __restrict__ hbuf, float* __restrict__ cbuf,
            unsigned long long* __restrict__ hx,
            int t0, int tagb, int first) {
    extern __shared__ float smem[];
    float* sW = smem;            // 32768 floats: [k][j][g]
    float* sH = smem + 32768;    // 2048 floats: hT[k][bb]
    float* sP = smem + 34816;    // 4608 floats: part[w][jj][36]

    const int tid = threadIdx.x;
    const int bid = blockIdx.x;
    const int grp = bid & 31;
    const int s   = bid >> 5;
    const int jj  = tid & 31;   // main identity: unit
    const int ks  = tid >> 5;   // main identity: k-slice
    const int w   = tid >> 6;   // wave id
    const int fb  = tid >> 5;   // finish identity: batch
    const int fj  = tid & 31;   // finish identity: unit
    const int bglob = grp * 8 + fb;
    const int unit  = s * 32 + fj;

    // load W slice into LDS (coalesced, linear)
    {
        const float4* Wgs = (const float4*)Wg_l + (size_t)s * 8192;
        float4* sW4 = (float4*)sW;
        #pragma unroll 4
        for (int i = tid; i < 8192; i += 256) sW4[i] = Wgs[i];
    }

    float creg = first ? 0.0f : cbuf[(size_t)bglob * H_ + unit];
    const float4* sW4 = (const float4*)sW;

    for (int tt = 0; tt < TC_; ++tt) {
        const int t = t0 + tt;

        // ---- phase A: gather h(t-1) into sH (hT[k][bb]) ----
        if (tt == 0) {
            if (first) {
                for (int i = tid; i < 2048; i += 256) sH[i] = 0.0f;
            } else {
                const int u = tid;
                #pragma unroll
                for (int bb = 0; bb < 8; ++bb)
                    sH[u * 8 + bb] = hbuf[((size_t)(grp * 8 + bb) * T_ + (t0 - 1)) * H_ + u];
            }
        } else {
            const unsigned exp_tag = (unsigned)(tagb + tt - 1);
            const unsigned long long* hs =
                hx + (size_t)(((tt - 1) & 1) * 32 + grp) * 2048;
            // scouts: tid 0..7 poll slice tid's sentinel (unit s*32+31, fb 7)
            if (tid < 8) {
                const unsigned long long* sent = hs + ((tid * 32 + 31) * 8 + 7);
                while ((unsigned)(__hip_atomic_load(sent, __ATOMIC_RELAXED, AG) >> 32)
                       != exp_tag)
                    __builtin_amdgcn_s_sleep(1);
            }
            __syncthreads();
            // one-shot bulk load + per-word verify
            const unsigned long long* my = hs + (size_t)tid * 8;
            unsigned long long v[8];
            #pragma unroll
            for (int b = 0; b < 8; ++b)
                v[b] = __hip_atomic_load(my + b, __ATOMIC_RELAXED, AG);
            #pragma unroll
            for (int b = 0; b < 8; ++b)
                while ((unsigned)(v[b] >> 32) != exp_tag)
                    v[b] = __hip_atomic_load(my + b, __ATOMIC_RELAXED, AG);
            #pragma unroll
            for (int b = 0; b < 8; ++b)
                sH[tid * 8 + b] = __uint_as_float((unsigned)v[b]);
        }

        // xp prefetch (finish identity; consumed in phase C)
        const size_t xrow = ((size_t)bglob * TC_ + tt) * G_ + unit;
        const float x0 = xp[xrow];
        const float x1 = xp[xrow + 256];
        const float x2 = xp[xrow + 512];
        const float x3 = xp[xrow + 768];

        __syncthreads();  // (b) sH ready (also covers initial sW load)

        // ---- phase B: main k-loop, all from LDS ----
        float4 a0 = {0,0,0,0}, a1 = {0,0,0,0}, a2 = {0,0,0,0}, a3 = {0,0,0,0};
        float4 a4 = {0,0,0,0}, a5 = {0,0,0,0}, a6 = {0,0,0,0}, a7 = {0,0,0,0};
        #pragma unroll 4
        for (int kk = 0; kk < 32; ++kk) {
            const int k = ks * 32 + kk;
            const float4 wv = sW4[k * 32 + jj];
            const float4 ha = *(const float4*)&sH[k * 8];
            const float4 hb = *(const float4*)&sH[k * 8 + 4];
            fma4(a0, ha.x, wv); fma4(a1, ha.y, wv);
            fma4(a2, ha.z, wv); fma4(a3, ha.w, wv);
            fma4(a4, hb.x, wv); fma4(a5, hb.y, wv);
            fma4(a6, hb.z, wv); fma4(a7, hb.w, wv);
        }
        // reduce ks-pairs within wave
        red4(a0); red4(a1); red4(a2); red4(a3);
        red4(a4); red4(a5); red4(a6); red4(a7);
        if ((tid & 63) < 32) {
            float4* pp = (float4*)&sP[(w * 32 + jj) * 36];
            pp[0] = a0; pp[1] = a1; pp[2] = a2; pp[3] = a3;
            pp[4] = a4; pp[5] = a5; pp[6] = a6; pp[7] = a7;
        }
        __syncthreads();  // (c) partials ready

        // ---- phase C: finish ----
        float4 g4;
        g4.x = x0; g4.y = x1; g4.z = x2; g4.w = x3;
        #pragma unroll
        for (int w2 = 0; w2 < 4; ++w2) {
            const float4 pw = *(const float4*)&sP[(w2 * 32 + fj) * 36 + fb * 4];
            g4.x += pw.x; g4.y += pw.y; g4.z += pw.z; g4.w += pw.w;
        }
        const float I = sigm(g4.x);
        const float F = sigm(g4.y);
        const float Gt = tanhf(g4.z);
        const float O = sigm(g4.w);
        creg = F * creg + I * Gt;
        const float hval = O * tanhf(creg);
        hbuf[((size_t)bglob * T_ + t) * H_ + unit] = hval;

        if (tt < TC_ - 1) {
            const unsigned long long pv =
                ((unsigned long long)(unsigned)(tagb + tt) << 32) | __float_as_uint(hval);
            __hip_atomic_store(hx + (size_t)((tt & 1) * 32 + grp) * 2048
                                  + (size_t)unit * 8 + fb,
                               pv, __ATOMIC_RELAXED, AG);
        }
    }

    cbuf[(size_t)bglob * H_ + unit] = creg;
}

// ---- final FC ----
extern "C" __global__ void __launch_bounds__(128)
fc_kernel(const float* __restrict__ hbuf, const float* __restrict__ fcw,
          const float* __restrict__ fcb, float* __restrict__ out) {
    __shared__ float wsm[256];
    const int tid = threadIdx.x;
    const int b = blockIdx.x;
    if (tid < 64) ((float4*)wsm)[tid] = ((const float4*)fcw)[tid];
    __syncthreads();
    if (tid < T_) {
        const float4* h4p = (const float4*)(hbuf + ((size_t)b * T_ + tid) * H_);
        const float4* w4p = (const float4*)wsm;
        float acc = fcb[0];
        #pragma unroll 8
        for (int k4 = 0; k4 < 64; ++k4) {
            float4 h4 = h4p[k4], w4 = w4p[k4];
            acc += h4.x * w4.x + h4.y * w4.y + h4.z * w4.z + h4.w * w4.w;
        }
        out[b * T_ + tid] = acc;
    }
}

extern "C" void kernel_launch(void* const* d_in, const int* in_sizes, int n_in,
                              void* d_out, int out_size, void* d_ws, size_t ws_size,
                              hipStream_t stream) {
    (void)in_sizes; (void)n_in; (void)out_size; (void)ws_size;
    const float* x    = (const float*)d_in[0];
    const float* Wih0 = (const float*)d_in[1];
    const float* Wihr = (const float*)d_in[2];
    const float* Whh  = (const float*)d_in[3];
    const float* bih  = (const float*)d_in[4];
    const float* bhh  = (const float*)d_in[5];
    const float* fcw  = (const float*)d_in[6];
    const float* fcb  = (const float*)d_in[7];
    float* out = (float*)d_out;
    float* ws  = (float*)d_ws;

    float* xp   = ws;
    float* hbuf = ws + XP_FLOATS;
    float* cbuf = hbuf + HBUF_FLOATS;
    float* wg   = cbuf + CBUF_FLOATS;
    unsigned long long* hx = (unsigned long long*)(ws + HX_OFF_FLOATS);

    // zero tags so no stale/garbage tag can alias a live one this launch
    hipMemsetAsync(hx, 0, HX_U64 * sizeof(unsigned long long), stream);
    hipLaunchKernelGGL(wt_kernel, dim3(WG_FLOATS / 256), dim3(256), 0, stream, Whh, wg);

    for (int l = 0; l < L_; ++l) {
        const int K = (l == 0) ? IN_ : H_;
        const float* src = (l == 0) ? x : hbuf;
        const float* Wih = (l == 0) ? Wih0 : (Wihr + (size_t)(l - 1) * G_ * H_);
        const float* Wg_l = wg + (size_t)l * (G_ * H_);
        for (int ch = 0; ch < NCH_; ++ch) {
            const int t0 = ch * TC_;
            const int tagb = (l * NCH_ + ch) * TC_ + 1;
            hipLaunchKernelGGL(proj_kernel, dim3(1024), dim3(256), 0, stream,
                               src, Wih, bih + l * G_, bhh + l * G_, xp, K, t0);
            hipLaunchKernelGGL(rec2_kernel, dim3(256), dim3(256), 157696, stream,
                               xp, Wg_l, hbuf, cbuf, hx, t0, tagb, ch == 0 ? 1 : 0);
        }
    }
    hipLaunchKernelGGL(fc_kernel, dim3(B_), dim3(128), 0, stream, hbuf, fcw, fcb, out);
}

// Round 7
// 2604.290 us; speedup vs baseline: 1.5130x; 1.1925x over previous
//
#include <hip/hip_runtime.h>

#define B_ 256
#define T_ 80
#define IN_ 39
#define H_ 256
#define G_ 1024
#define L_ 5
#define TC_ 16
#define NCH_ 5

#define XP_FLOATS   (B_ * TC_ * G_)     // 4,194,304
#define HBUF_FLOATS (B_ * T_ * H_)      // 5,242,880
#define CBUF_FLOATS (B_ * H_)           // 65,536
#define WG_FLOATS   (L_ * G_ * H_)      // 1,310,720
#define HX_FLOATS   (2 * 32 * 2048)     // 131,072
#define CNT_OFF_FLOATS (XP_FLOATS + HBUF_FLOATS + CBUF_FLOATS + WG_FLOATS + HX_FLOATS)

#define AG __HIP_MEMORY_SCOPE_AGENT

__device__ __forceinline__ float sigm(float x) { return 1.0f / (1.0f + expf(-x)); }
__device__ __forceinline__ void fma4(float4& a, float s, const float4& w) {
    a.x = fmaf(s, w.x, a.x); a.y = fmaf(s, w.y, a.y);
    a.z = fmaf(s, w.z, a.z); a.w = fmaf(s, w.w, a.w);
}
__device__ __forceinline__ void red4(float4& a) {
    a.x += __shfl_xor(a.x, 32); a.y += __shfl_xor(a.y, 32);
    a.z += __shfl_xor(a.z, 32); a.w += __shfl_xor(a.w, 32);
}
__device__ __forceinline__ float lo32(unsigned long long v) { return __uint_as_float((unsigned)v); }
__device__ __forceinline__ float hi32(unsigned long long v) { return __uint_as_float((unsigned)(v >> 32)); }

// ---- Wg: per-slice interleaved W_hh: Wg[l][s][k][j][g] = Whh[l][g*256+s*32+j][k] ----
extern "C" __global__ void __launch_bounds__(256)
wt_kernel(const float* __restrict__ Whh, float* __restrict__ Wg) {
    const int gid = blockIdx.x * 256 + threadIdx.x;
    const int g4 = gid & 3;
    const int j  = (gid >> 2) & 31;
    const int k  = (gid >> 7) & 255;
    const int s  = (gid >> 15) & 7;
    const int l  = gid >> 18;
    Wg[gid] = Whh[((size_t)(l * 1024 + g4 * 256 + s * 32 + j)) * 256 + k];
}

// ---- projection GEMM (unchanged) ----
extern "C" __global__ void __launch_bounds__(256)
proj_kernel(const float* __restrict__ src, const float* __restrict__ Wih,
            const float* __restrict__ bihl, const float* __restrict__ bhhl,
            float* __restrict__ xp, int K, int t0) {
    __shared__ float As[16 * 68];
    __shared__ float Bs[16 * 68];
    const int tid = threadIdx.x;
    const int mt = blockIdx.x >> 4, nt = blockIdx.x & 15;
    const int tx = tid & 15, ty = tid >> 4;
    const int lr = tid >> 2, lc4 = (tid & 3) << 2;

    const int ar = mt * 64 + lr;
    const int ab = ar >> 4;
    const int at = t0 + (ar & 15);
    const float* arow = src + ((size_t)ab * T_ + at) * K;
    const float* brow = Wih + (size_t)(nt * 64 + lr) * K;

    float acc[4][4];
    #pragma unroll
    for (int i = 0; i < 4; ++i)
        #pragma unroll
        for (int j = 0; j < 4; ++j) acc[i][j] = 0.0f;

    for (int k0 = 0; k0 < K; k0 += 16) {
        __syncthreads();
        if (K == IN_) {
            #pragma unroll
            for (int i = 0; i < 4; ++i) {
                int k = k0 + lc4 + i;
                As[(lc4 + i) * 68 + lr] = (k < IN_) ? arow[k] : 0.0f;
                Bs[(lc4 + i) * 68 + lr] = (k < IN_) ? brow[k] : 0.0f;
            }
        } else {
            float4 av = *(const float4*)(arow + k0 + lc4);
            float4 bv = *(const float4*)(brow + k0 + lc4);
            As[(lc4 + 0) * 68 + lr] = av.x;
            As[(lc4 + 1) * 68 + lr] = av.y;
            As[(lc4 + 2) * 68 + lr] = av.z;
            As[(lc4 + 3) * 68 + lr] = av.w;
            Bs[(lc4 + 0) * 68 + lr] = bv.x;
            Bs[(lc4 + 1) * 68 + lr] = bv.y;
            Bs[(lc4 + 2) * 68 + lr] = bv.z;
            Bs[(lc4 + 3) * 68 + lr] = bv.w;
        }
        __syncthreads();
        #pragma unroll
        for (int kk = 0; kk < 16; ++kk) {
            float4 a4 = *(const float4*)&As[kk * 68 + ty * 4];
            float4 b4 = *(const float4*)&Bs[kk * 68 + tx * 4];
            acc[0][0] += a4.x * b4.x; acc[0][1] += a4.x * b4.y;
            acc[0][2] += a4.x * b4.z; acc[0][3] += a4.x * b4.w;
            acc[1][0] += a4.y * b4.x; acc[1][1] += a4.y * b4.y;
            acc[1][2] += a4.y * b4.z; acc[1][3] += a4.y * b4.w;
            acc[2][0] += a4.z * b4.x; acc[2][1] += a4.z * b4.y;
            acc[2][2] += a4.z * b4.z; acc[2][3] += a4.z * b4.w;
            acc[3][0] += a4.w * b4.x; acc[3][1] += a4.w * b4.y;
            acc[3][2] += a4.w * b4.z; acc[3][3] += a4.w * b4.w;
        }
    }
    const int col = nt * 64 + tx * 4;
    const float bs0 = bihl[col + 0] + bhhl[col + 0];
    const float bs1 = bihl[col + 1] + bhhl[col + 1];
    const float bs2 = bihl[col + 2] + bhhl[col + 2];
    const float bs3 = bihl[col + 3] + bhhl[col + 3];
    #pragma unroll
    for (int i = 0; i < 4; ++i) {
        const int row = mt * 64 + ty * 4 + i;
        float4 o;
        o.x = acc[i][0] + bs0; o.y = acc[i][1] + bs1;
        o.z = acc[i][2] + bs2; o.w = acc[i][3] + bs3;
        *(float4*)&xp[(size_t)row * G_ + col] = o;
    }
}

// ---- recurrence: W in REGISTERS, 512 threads (2 waves/SIMD), r4 counter sync ----
// grid 256 = 32 groups (8 batches) x 8 slices (32 units x 4 gates).
// Each thread (jj=unit, ks=k-slice of 16) holds its 16xfloat4 W fragment in
// VGPRs (fully unrolled -> static indexing, no scratch). LDS only h + partials
// (45KB). Sync = round-4 scheme verbatim (best measured): relaxed AG data
// stores, vmcnt drain + barrier, tid0 fetch_add on padded per-group counter.
extern "C" __global__ void __launch_bounds__(512, 2)
rec3_kernel(const float* __restrict__ xp, const float* __restrict__ Wg_l,
            float* __restrict__ hbuf, float* __restrict__ cbuf,
            float* __restrict__ hx, int* __restrict__ cnt,
            int t0, int chkb, int first) {
    __shared__ float sH[2048];          // hT[k][bb]  (8 KB)
    __shared__ float sP[8 * 32 * 36];   // part[w][jj][36] (36 KB)

    const int tid = threadIdx.x;
    const int bid = blockIdx.x;
    const int grp = bid & 31;
    const int s   = bid >> 5;
    const int jj  = tid & 31;       // main identity: unit
    const int ks  = tid >> 5;       // main identity: k-slice (0..15)
    const int w   = tid >> 6;       // wave id (0..7)
    const int fb  = (tid >> 5) & 7; // finish identity: batch (tid<256)
    const int fj  = tid & 31;       // finish identity: unit
    const int bglob = grp * 8 + fb;
    const int unit  = s * 32 + fj;
    int* cnt_g = cnt + grp * 32;    // one counter per 128B line

    // W fragment into registers: wreg[kk] = 4 gates of unit jj at k = ks*16+kk
    const float4* Wg4 = (const float4*)Wg_l + (size_t)s * 8192;
    float4 wreg[16];
    #pragma unroll
    for (int kk = 0; kk < 16; ++kk)
        wreg[kk] = Wg4[(size_t)(ks * 16 + kk) * 32 + jj];

    float creg = 0.0f;
    if (tid < 256 && !first) creg = cbuf[(size_t)bglob * H_ + unit];

    const float4* sH4 = (const float4*)sH;

    for (int tt = 0; tt < TC_; ++tt) {
        const int t = t0 + tt;

        // ---- phase A: gather h(t-1) into sH (hT[k][bb]) ----
        if (tt == 0) {
            if (first) {
                for (int i = tid; i < 2048; i += 512) sH[i] = 0.0f;
            } else if (tid < 256) {
                const int u = tid;
                #pragma unroll
                for (int bb = 0; bb < 8; ++bb)
                    sH[u * 8 + bb] = hbuf[((size_t)(grp * 8 + bb) * T_ + (t0 - 1)) * H_ + u];
            }
        } else {
            if (tid == 0) {
                const int tgt = 8 * (chkb + tt);
                while (__hip_atomic_load(cnt_g, __ATOMIC_RELAXED, AG) < tgt)
                    __builtin_amdgcn_s_sleep(1);
            }
            __syncthreads();
            if (tid < 256) {
                const unsigned long long* hs =
                    (const unsigned long long*)(hx + (size_t)(((tt - 1) & 1) * 32 + grp) * 2048);
                const int u = tid;
                unsigned long long v0 = __hip_atomic_load(hs + u * 4 + 0, __ATOMIC_RELAXED, AG);
                unsigned long long v1 = __hip_atomic_load(hs + u * 4 + 1, __ATOMIC_RELAXED, AG);
                unsigned long long v2 = __hip_atomic_load(hs + u * 4 + 2, __ATOMIC_RELAXED, AG);
                unsigned long long v3 = __hip_atomic_load(hs + u * 4 + 3, __ATOMIC_RELAXED, AG);
                float4 fa, fbv;
                fa.x = lo32(v0); fa.y = hi32(v0); fa.z = lo32(v1); fa.w = hi32(v1);
                fbv.x = lo32(v2); fbv.y = hi32(v2); fbv.z = lo32(v3); fbv.w = hi32(v3);
                *(float4*)&sH[u * 8] = fa;
                *(float4*)&sH[u * 8 + 4] = fbv;
            }
        }

        // xp prefetch (finish identity; consumed in phase C)
        float x0 = 0.f, x1 = 0.f, x2 = 0.f, x3 = 0.f;
        if (tid < 256) {
            const size_t xrow = ((size_t)bglob * TC_ + tt) * G_ + unit;
            x0 = xp[xrow];
            x1 = xp[xrow + 256];
            x2 = xp[xrow + 512];
            x3 = xp[xrow + 768];
        }

        __syncthreads();  // (b) sH ready

        // ---- phase B: k-loop, W from registers, h broadcast from LDS ----
        float4 a0 = {0,0,0,0}, a1 = {0,0,0,0}, a2 = {0,0,0,0}, a3 = {0,0,0,0};
        float4 a4 = {0,0,0,0}, a5 = {0,0,0,0}, a6 = {0,0,0,0}, a7 = {0,0,0,0};
        #pragma unroll
        for (int kk = 0; kk < 16; ++kk) {
            const int k = ks * 16 + kk;
            const float4 wv = wreg[kk];
            const float4 ha = sH4[k * 2];
            const float4 hb = sH4[k * 2 + 1];
            fma4(a0, ha.x, wv); fma4(a1, ha.y, wv);
            fma4(a2, ha.z, wv); fma4(a3, ha.w, wv);
            fma4(a4, hb.x, wv); fma4(a5, hb.y, wv);
            fma4(a6, hb.z, wv); fma4(a7, hb.w, wv);
        }
        // reduce ks-pairs within wave (lane ^ 32 flips ks bit0)
        red4(a0); red4(a1); red4(a2); red4(a3);
        red4(a4); red4(a5); red4(a6); red4(a7);
        if ((tid & 63) < 32) {
            float4* pp = (float4*)&sP[(w * 32 + jj) * 36];
            pp[0] = a0; pp[1] = a1; pp[2] = a2; pp[3] = a3;
            pp[4] = a4; pp[5] = a5; pp[6] = a6; pp[7] = a7;
        }
        __syncthreads();  // (c) partials ready

        // ---- phase C: finish (tid < 256) ----
        if (tid < 256) {
            float4 g4;
            g4.x = x0; g4.y = x1; g4.z = x2; g4.w = x3;
            #pragma unroll
            for (int w2 = 0; w2 < 8; ++w2) {
                const float4 pw = *(const float4*)&sP[(w2 * 32 + fj) * 36 + fb * 4];
                g4.x += pw.x; g4.y += pw.y; g4.z += pw.z; g4.w += pw.w;
            }
            const float I = sigm(g4.x);
            const float F = sigm(g4.y);
            const float Gt = tanhf(g4.z);
            const float O = sigm(g4.w);
            creg = F * creg + I * Gt;
            const float hval = O * tanhf(creg);
            hbuf[((size_t)bglob * T_ + t) * H_ + unit] = hval;

            if (tt < TC_ - 1) {
                __hip_atomic_store(hx + (size_t)((tt & 1) * 32 + grp) * 2048 + unit * 8 + fb,
                                   hval, __ATOMIC_RELAXED, AG);
            }
        }

        if (tt < TC_ - 1) {
            asm volatile("s_waitcnt vmcnt(0)" ::: "memory");
            __syncthreads();  // (d) all publishes drained
            if (tid == 0)
                __hip_atomic_fetch_add(cnt_g, 1, __ATOMIC_RELAXED, AG);
        }
    }

    if (tid < 256) cbuf[(size_t)bglob * H_ + unit] = creg;
}

// ---- final FC ----
extern "C" __global__ void __launch_bounds__(128)
fc_kernel(const float* __restrict__ hbuf, const float* __restrict__ fcw,
          const float* __restrict__ fcb, float* __restrict__ out) {
    __shared__ float wsm[256];
    const int tid = threadIdx.x;
    const int b = blockIdx.x;
    if (tid < 64) ((float4*)wsm)[tid] = ((const float4*)fcw)[tid];
    __syncthreads();
    if (tid < T_) {
        const float4* h4p = (const float4*)(hbuf + ((size_t)b * T_ + tid) * H_);
        const float4* w4p = (const float4*)wsm;
        float acc = fcb[0];
        #pragma unroll 8
        for (int k4 = 0; k4 < 64; ++k4) {
            float4 h4 = h4p[k4], w4 = w4p[k4];
            acc += h4.x * w4.x + h4.y * w4.y + h4.z * w4.z + h4.w * w4.w;
        }
        out[b * T_ + tid] = acc;
    }
}

extern "C" void kernel_launch(void* const* d_in, const int* in_sizes, int n_in,
                              void* d_out, int out_size, void* d_ws, size_t ws_size,
                              hipStream_t stream) {
    (void)in_sizes; (void)n_in; (void)out_size; (void)ws_size;
    const float* x    = (const float*)d_in[0];
    const float* Wih0 = (const float*)d_in[1];
    const float* Wihr = (const float*)d_in[2];
    const float* Whh  = (const float*)d_in[3];
    const float* bih  = (const float*)d_in[4];
    const float* bhh  = (const float*)d_in[5];
    const float* fcw  = (const float*)d_in[6];
    const float* fcb  = (const float*)d_in[7];
    float* out = (float*)d_out;
    float* ws  = (float*)d_ws;

    float* xp   = ws;
    float* hbuf = ws + XP_FLOATS;
    float* cbuf = hbuf + HBUF_FLOATS;
    float* wg   = cbuf + CBUF_FLOATS;
    float* hx   = wg + WG_FLOATS;
    int*   cnt  = (int*)(ws + CNT_OFF_FLOATS);

    hipMemsetAsync(cnt, 0, 32 * 32 * sizeof(int), stream);
    hipLaunchKernelGGL(wt_kernel, dim3(WG_FLOATS / 256), dim3(256), 0, stream, Whh, wg);

    for (int l = 0; l < L_; ++l) {
        const int K = (l == 0) ? IN_ : H_;
        const float* src = (l == 0) ? x : hbuf;
        const float* Wih = (l == 0) ? Wih0 : (Wihr + (size_t)(l - 1) * G_ * H_);
        const float* Wg_l = wg + (size_t)l * (G_ * H_);
        for (int ch = 0; ch < NCH_; ++ch) {
            const int t0 = ch * TC_;
            const int chkb = (l * NCH_ + ch) * (TC_ - 1);
            hipLaunchKernelGGL(proj_kernel, dim3(1024), dim3(256), 0, stream,
                               src, Wih, bih + l * G_, bhh + l * G_, xp, K, t0);
            hipLaunchKernelGGL(rec3_kernel, dim3(256), dim3(512), 0, stream,
                               xp, Wg_l, hbuf, cbuf, hx, cnt, t0, chkb, ch == 0 ? 1 : 0);
        }
    }
    hipLaunchKernelGGL(fc_kernel, dim3(B_), dim3(128), 0, stream, hbuf, fcw, fcb, out);
}